// Round 2
// baseline (6955.849 us; speedup 1.0000x reference)
//
#include <hip/hip_runtime.h>
#include <hip/hip_bf16.h>

#define NB    128
#define LSEQ  512
#define HIDN  512
#define EMB   256
#define DTOT  768
#define GRID_MAIN 128   // cooperative blocks; block wg owns hidden units [wg*4, wg*4+4)

typedef __attribute__((ext_vector_type(8))) short  short8;   // MFMA A/B frag (8 bf16)
typedef __attribute__((ext_vector_type(4))) float  floatx4;  // MFMA C/D frag
typedef __attribute__((ext_vector_type(4))) unsigned int uintx4;

__device__ __forceinline__ unsigned short f2bf(float f) {   // RNE
  unsigned u = __builtin_bit_cast(unsigned, f);
  unsigned r = u + 0x7fffu + ((u >> 16) & 1u);
  return (unsigned short)(r >> 16);
}
// pack two floats -> two bf16 (round-half-away) in one v_perm
__device__ __forceinline__ unsigned bfpair(float lo, float hi) {
  unsigned a = __builtin_bit_cast(unsigned, lo) + 0x8000u;
  unsigned b = __builtin_bit_cast(unsigned, hi) + 0x8000u;
  return __builtin_amdgcn_perm(b, a, 0x07060302u);  // [lo.b2,lo.b3,hi.b2,hi.b3]
}
__device__ __forceinline__ short8 pack8(float4 u, float4 v) {
  union { short8 s; uintx4 w; } cv;
  cv.w[0] = bfpair(u.x, u.y); cv.w[1] = bfpair(u.z, u.w);
  cv.w[2] = bfpair(v.x, v.y); cv.w[3] = bfpair(v.z, v.w);
  return cv.s;
}
__device__ __forceinline__ float sigmoid_f(float x) { return 1.f / (1.f + __expf(-x)); }
__device__ __forceinline__ float tanh_f(float x) {
  float e = __expf(2.f * x);
  return 1.f - 2.f / (e + 1.f);
}

// Grid: 128 blocks x 256 thr (4 waves). Wave wv owns batch rows [wv*32, wv*32+32).
// MFMA: D = A*B, A = W^T fragment (M=16 gate cols), B = hx fragment (N=16 batch).
// C/D layout => lane (l15,l4) acc[r] = z[gate r][unit wg*4+l4][batch mbase(+16)+l15]:
// all 4 gates of one unit land in one lane's acc — no LDS transpose needed.
__global__ void __launch_bounds__(256, 1)
lstm_main(const int* __restrict__ X, const float* __restrict__ E,
          const float* __restrict__ Wi, const float* __restrict__ bi,
          const float* __restrict__ Wf, const float* __restrict__ bf_,
          const float* __restrict__ Wo, const float* __restrict__ bo,
          const float* __restrict__ Wh, const float* __restrict__ bh,
          float* __restrict__ out, unsigned short* __restrict__ hb,
          int* cnt, int* flag) {
  const int wg   = blockIdx.x;
  const int tid  = threadIdx.x;
  const int lane = tid & 63;
  const int wv   = tid >> 6;
  const int l15  = lane & 15;
  const int l4   = lane >> 4;
  const int mbase = wv * 32;

  // --- W fragments (A operand), loaded once into 96 VGPRs ---
  // A[m=l15][k=l4*8+j] = W_g[k][jcol] for gate col c = wg*16 + l15, c = j*4+g
  const int cg = wg * 16 + l15;
  const int jcol = cg >> 2, g = cg & 3;
  const float* Wg = (g == 0) ? Wi : (g == 1) ? Wf : (g == 2) ? Wo : Wh;
  short8 bfrag[24];
#pragma unroll
  for (int kt = 0; kt < 24; ++kt) {
    union { short8 s; unsigned short us[8]; } cv;
#pragma unroll
    for (int e = 0; e < 8; ++e) {
      int k = kt * 32 + l4 * 8 + e;
      cv.us[e] = f2bf(Wg[(size_t)k * HIDN + jcol]);
    }
    bfrag[kt] = cv.s;
  }

  const int jglob = wg * 4 + l4;    // this lane's hidden unit (output side)
  const float bI = bi[jglob], bF = bf_[jglob], bO = bo[jglob], bH = bh[jglob];

  float c0 = 0.f, c1 = 0.f;        // cell state (q=0: row l15, q=1: row 16+l15)

  // --- initial x fragments (t = 0), gathered from fp32 E on the fly ---
  short8 xf[8][2];
#pragma unroll
  for (int q = 0; q < 2; ++q) {
    int n = mbase + q * 16 + l15;
    int idx = X[(size_t)n * LSEQ + 0];
    const float* er = E + (size_t)idx * EMB + l4 * 8;
#pragma unroll
    for (int kt = 0; kt < 8; ++kt) {
      float4 u = *(const float4*)(er + kt * 32);
      float4 v = *(const float4*)(er + kt * 32 + 4);
      xf[kt][q] = pack8(u, v);
    }
  }

  unsigned short* hcur = hb;                       // zeroed by host memset: h_0 = 0
  unsigned short* hnxt = hb + (size_t)NB * HIDN;

  for (int t = 0; t < LSEQ; ++t) {
    // --- h fragments (B operand): B[k=l4*8+j][n=l15] from hcur[n][k] ---
    const unsigned short* h0p = hcur + (size_t)(mbase + l15) * HIDN + l4 * 8;
    const unsigned short* h1p = hcur + (size_t)(mbase + 16 + l15) * HIDN + l4 * 8;
    short8 hf0[16], hf1[16];
#pragma unroll
    for (int kt = 0; kt < 16; ++kt) hf0[kt] = *(const short8*)(h0p + kt * 32);
#pragma unroll
    for (int kt = 0; kt < 16; ++kt) hf1[kt] = *(const short8*)(h1p + kt * 32);

    floatx4 acc0 = {0.f, 0.f, 0.f, 0.f};
    floatx4 acc1 = {0.f, 0.f, 0.f, 0.f};
    // x part first (operands already in registers)
#pragma unroll
    for (int kt = 0; kt < 8; ++kt) {
      acc0 = __builtin_amdgcn_mfma_f32_16x16x32_bf16(bfrag[16 + kt], xf[kt][0], acc0, 0, 0, 0);
      acc1 = __builtin_amdgcn_mfma_f32_16x16x32_bf16(bfrag[16 + kt], xf[kt][1], acc1, 0, 0, 0);
    }
#pragma unroll
    for (int kt = 0; kt < 16; ++kt) {
      acc0 = __builtin_amdgcn_mfma_f32_16x16x32_bf16(bfrag[kt], hf0[kt], acc0, 0, 0, 0);
      acc1 = __builtin_amdgcn_mfma_f32_16x16x32_bf16(bfrag[kt], hf1[kt], acc1, 0, 0, 0);
    }

    // --- gates: acc[r] = z for gate r (i,f,o,h) of unit jglob, batch n ---
#pragma unroll
    for (int q = 0; q < 2; ++q) {
      floatx4 z = q ? acc1 : acc0;
      float ig = sigmoid_f(z[0] + bI);
      float fg = sigmoid_f(z[1] + bF);
      float og = sigmoid_f(z[2] + bO);
      float gg = tanh_f(z[3] + bH);
      float cs = q ? c1 : c0;
      cs = fg * cs + ig * gg;
      if (q) c1 = cs; else c0 = cs;
      float h = og * tanh_f(cs);
      int n = mbase + q * 16 + l15;
      hnxt[(size_t)n * HIDN + jglob] = f2bf(h);
      if (t == LSEQ - 1) out[(size_t)n * HIDN + jglob] = h;
    }

    if (t == LSEQ - 1) break;

    // --- prefetch + convert x fragments for step t+1 (off critical path) ---
#pragma unroll
    for (int q = 0; q < 2; ++q) {
      int n = mbase + q * 16 + l15;
      int idx = X[(size_t)n * LSEQ + t + 1];
      const float* er = E + (size_t)idx * EMB + l4 * 8;
#pragma unroll
      for (int kt = 0; kt < 8; ++kt) {
        float4 u = *(const float4*)(er + kt * 32);
        float4 v = *(const float4*)(er + kt * 32 + 4);
        xf[kt][q] = pack8(u, v);
      }
    }

    { unsigned short* tmp = hcur; hcur = hnxt; hnxt = tmp; }

    // --- grid barrier (monotonic count; fence pair publishes/imports h) ---
    __syncthreads();
    if (tid == 0) {
      __threadfence();   // publish this block's h stores (L2 writeback, agent scope)
      int prev = __hip_atomic_fetch_add(cnt, 1, __ATOMIC_RELAXED, __HIP_MEMORY_SCOPE_AGENT);
      if (prev == (t + 1) * GRID_MAIN - 1) {
        __hip_atomic_store(flag, t + 1, __ATOMIC_RELAXED, __HIP_MEMORY_SCOPE_AGENT);
      } else {
        while (__hip_atomic_load(flag, __ATOMIC_RELAXED, __HIP_MEMORY_SCOPE_AGENT) < t + 1) {}
      }
      __threadfence();   // import other blocks' h stores (cache invalidate)
    }
    __syncthreads();
  }
}

// ws layout: [0] cnt, [4] flag, [256] hb double buffer (2*128*512*2 B = 262144).
// Total ws use: 262,400 B.
extern "C" void kernel_launch(void* const* d_in, const int* in_sizes, int n_in,
                              void* d_out, int out_size, void* d_ws, size_t ws_size,
                              hipStream_t stream) {
  const int*   X  = (const int*)d_in[0];
  const float* E  = (const float*)d_in[1];
  const float* Wi = (const float*)d_in[2];
  const float* bi = (const float*)d_in[3];
  const float* Wf = (const float*)d_in[4];
  const float* bf = (const float*)d_in[5];
  const float* Wo = (const float*)d_in[6];
  const float* bo = (const float*)d_in[7];
  const float* Wh = (const float*)d_in[8];
  const float* bh = (const float*)d_in[9];
  float* out = (float*)d_out;

  char* ws = (char*)d_ws;
  int* cnt = (int*)ws;
  int* flag = (int*)(ws + 4);
  unsigned short* hb = (unsigned short*)(ws + 256);

  hipMemsetAsync(ws, 0, 256 + 2 * NB * HIDN * sizeof(unsigned short), stream);

  void* args[] = { (void*)&X, (void*)&E,
                   (void*)&Wi, (void*)&bi, (void*)&Wf, (void*)&bf,
                   (void*)&Wo, (void*)&bo, (void*)&Wh, (void*)&bh,
                   (void*)&out, (void*)&hb, (void*)&cnt, (void*)&flag };
  hipLaunchCooperativeKernel(reinterpret_cast<void*>(lstm_main),
                             dim3(GRID_MAIN), dim3(256), args, 0, stream);
}

// Round 3
// 5885.376 us; speedup vs baseline: 1.1819x; 1.1819x over previous
//
#include <hip/hip_runtime.h>
#include <hip/hip_bf16.h>

#define NB    128
#define LSEQ  512
#define HIDN  512
#define EMB   256
#define DTOT  768
#define GRID_MAIN 128   // cooperative blocks; block wg owns hidden units [wg*4, wg*4+4)

typedef __attribute__((ext_vector_type(8))) short  short8;   // MFMA A/B frag (8 bf16)
typedef __attribute__((ext_vector_type(4))) float  floatx4;  // MFMA C/D frag
typedef __attribute__((ext_vector_type(4))) unsigned int uintx4;

__device__ __forceinline__ unsigned short f2bf(float f) {   // RNE
  unsigned u = __builtin_bit_cast(unsigned, f);
  unsigned r = u + 0x7fffu + ((u >> 16) & 1u);
  return (unsigned short)(r >> 16);
}
// pack two floats -> two bf16 in one v_perm (round-half-up: |err| <= 1 ulp RNE)
__device__ __forceinline__ unsigned bfpair(float lo, float hi) {
  unsigned a = __builtin_bit_cast(unsigned, lo) + 0x8000u;
  unsigned b = __builtin_bit_cast(unsigned, hi) + 0x8000u;
  return __builtin_amdgcn_perm(b, a, 0x07060302u);
}
__device__ __forceinline__ short8 pack8(float4 u, float4 v) {
  union { short8 s; uintx4 w; } cv;
  cv.w[0] = bfpair(u.x, u.y); cv.w[1] = bfpair(u.z, u.w);
  cv.w[2] = bfpair(v.x, v.y); cv.w[3] = bfpair(v.z, v.w);
  return cv.s;
}
__device__ __forceinline__ float sigmoid_f(float x) { return 1.f / (1.f + __expf(-x)); }
__device__ __forceinline__ float tanh_f(float x) {
  float e = __expf(2.f * x);
  return 1.f - 2.f / (e + 1.f);
}

// xe[t][n][e] = bf16(E[X[n][t]][e]) — time-major, k-contiguous for B-fragment loads
__global__ void prep_x_kernel(const int* __restrict__ X, const float* __restrict__ E,
                              unsigned short* __restrict__ xe) {
  int t = blockIdx.x, n = blockIdx.y;
  int row = X[(size_t)n * LSEQ + t];
  float4 v = ((const float4*)(E + (size_t)row * EMB))[threadIdx.x];
  ushort4 o;
  o.x = f2bf(v.x); o.y = f2bf(v.y); o.z = f2bf(v.z); o.w = f2bf(v.w);
  *(ushort4*)(xe + ((size_t)t * NB + n) * EMB + threadIdx.x * 4) = o;
}

// ---- main cooperative recurrence kernel ----------------------------------
// Grid: 128 blocks x 256 thr (4 waves). Wave wv owns batch rows [wv*32,+32).
// MFMA: D = A*B, A = W^T fragment (M=16 gate cols), B = hx fragment (N=16 batch).
// C/D layout: lane (l15,l4) acc[r] = z[gate r][unit wg*4+l4][batch ...+l15] —
// all 4 gates of one unit in one lane's acc, no LDS transpose.
// Barrier: distributed per-block arrival slots (own cacheline each), wave-0
// parallel poll — no same-line atomic serialization.
template <bool USE_XE>
__global__ void __launch_bounds__(256, 1)
lstm_main(const int* __restrict__ X, const float* __restrict__ E,
          const unsigned short* __restrict__ xe,
          const float* __restrict__ Wi, const float* __restrict__ bi,
          const float* __restrict__ Wf, const float* __restrict__ bf_,
          const float* __restrict__ Wo, const float* __restrict__ bo,
          const float* __restrict__ Wh, const float* __restrict__ bh,
          float* __restrict__ out, unsigned short* __restrict__ hb,
          int* __restrict__ arrive) {
  const int wg   = blockIdx.x;
  const int tid  = threadIdx.x;
  const int lane = tid & 63;
  const int wv   = tid >> 6;
  const int l15  = lane & 15;
  const int l4   = lane >> 4;
  const int mbase = wv * 32;

  // --- W fragments (A operand), loaded once into 96 VGPRs ---
  const int cg = wg * 16 + l15;          // gate column c = j*4+g
  const int jcol = cg >> 2, g = cg & 3;
  const float* Wg = (g == 0) ? Wi : (g == 1) ? Wf : (g == 2) ? Wo : Wh;
  short8 bfrag[24];
#pragma unroll
  for (int kt = 0; kt < 24; ++kt) {
    union { short8 s; unsigned short us[8]; } cv;
#pragma unroll
    for (int e = 0; e < 8; ++e) {
      int k = kt * 32 + l4 * 8 + e;
      cv.us[e] = f2bf(Wg[(size_t)k * HIDN + jcol]);
    }
    bfrag[kt] = cv.s;
  }

  const int jglob = wg * 4 + l4;
  const float bI = bi[jglob], bF = bf_[jglob], bO = bo[jglob], bH = bh[jglob];
  float c0 = 0.f, c1 = 0.f;

  // --- initial x fragments (t = 0) ---
  short8 xf[8][2];
#pragma unroll
  for (int q = 0; q < 2; ++q) {
    int n = mbase + q * 16 + l15;
    if (USE_XE) {
      const unsigned short* xr = xe + (size_t)n * EMB + l4 * 8;
#pragma unroll
      for (int kt = 0; kt < 8; ++kt) xf[kt][q] = *(const short8*)(xr + kt * 32);
    } else {
      int idx = X[(size_t)n * LSEQ + 0];
      const float* er = E + (size_t)idx * EMB + l4 * 8;
#pragma unroll
      for (int kt = 0; kt < 8; ++kt) {
        float4 u = *(const float4*)(er + kt * 32);
        float4 v = *(const float4*)(er + kt * 32 + 4);
        xf[kt][q] = pack8(u, v);
      }
    }
  }

  unsigned short* hcur = hb;                       // zeroed by host memset: h_0 = 0
  unsigned short* hnxt = hb + (size_t)NB * HIDN;

  for (int t = 0; t < LSEQ; ++t) {
    // --- h fragments (B operand): B[k=l4*8+j][n=l15] from hcur[n][k] ---
    const unsigned short* h0p = hcur + (size_t)(mbase + l15) * HIDN + l4 * 8;
    const unsigned short* h1p = hcur + (size_t)(mbase + 16 + l15) * HIDN + l4 * 8;
    short8 hf0[16], hf1[16];
#pragma unroll
    for (int kt = 0; kt < 16; ++kt) hf0[kt] = *(const short8*)(h0p + kt * 32);
#pragma unroll
    for (int kt = 0; kt < 16; ++kt) hf1[kt] = *(const short8*)(h1p + kt * 32);

    floatx4 acc0 = {0.f, 0.f, 0.f, 0.f};
    floatx4 acc1 = {0.f, 0.f, 0.f, 0.f};
#pragma unroll
    for (int kt = 0; kt < 8; ++kt) {   // x part first (already in registers)
      acc0 = __builtin_amdgcn_mfma_f32_16x16x32_bf16(bfrag[16 + kt], xf[kt][0], acc0, 0, 0, 0);
      acc1 = __builtin_amdgcn_mfma_f32_16x16x32_bf16(bfrag[16 + kt], xf[kt][1], acc1, 0, 0, 0);
    }
#pragma unroll
    for (int kt = 0; kt < 16; ++kt) {
      acc0 = __builtin_amdgcn_mfma_f32_16x16x32_bf16(bfrag[kt], hf0[kt], acc0, 0, 0, 0);
      acc1 = __builtin_amdgcn_mfma_f32_16x16x32_bf16(bfrag[kt], hf1[kt], acc1, 0, 0, 0);
    }

    // --- gates ---
#pragma unroll
    for (int q = 0; q < 2; ++q) {
      floatx4 z = q ? acc1 : acc0;
      float ig = sigmoid_f(z[0] + bI);
      float fg = sigmoid_f(z[1] + bF);
      float og = sigmoid_f(z[2] + bO);
      float gg = tanh_f(z[3] + bH);
      float cs = q ? c1 : c0;
      cs = fg * cs + ig * gg;
      if (q) c1 = cs; else c0 = cs;
      float h = og * tanh_f(cs);
      int n = mbase + q * 16 + l15;
      hnxt[(size_t)n * HIDN + jglob] = f2bf(h);
      if (t == LSEQ - 1) out[(size_t)n * HIDN + jglob] = h;
    }

    if (t == LSEQ - 1) break;

    // --- prefetch x fragments for step t+1 (loads overlap the barrier wait) ---
#pragma unroll
    for (int q = 0; q < 2; ++q) {
      int n = mbase + q * 16 + l15;
      if (USE_XE) {
        const unsigned short* xr = xe + ((size_t)(t + 1) * NB + n) * EMB + l4 * 8;
#pragma unroll
        for (int kt = 0; kt < 8; ++kt) xf[kt][q] = *(const short8*)(xr + kt * 32);
      } else {
        int idx = X[(size_t)n * LSEQ + t + 1];
        const float* er = E + (size_t)idx * EMB + l4 * 8;
#pragma unroll
        for (int kt = 0; kt < 8; ++kt) {
          float4 u = *(const float4*)(er + kt * 32);
          float4 v = *(const float4*)(er + kt * 32 + 4);
          xf[kt][q] = pack8(u, v);
        }
      }
    }

    { unsigned short* tmp = hcur; hcur = hnxt; hnxt = tmp; }

    // --- distributed grid barrier: parallel arrival slots, wave-0 poll ---
    const int gen = t + 1;
    __syncthreads();
    if (tid == 0) {
      __threadfence();  // publish this block's h stores (L2 writeback, agent scope)
      __hip_atomic_store(&arrive[wg * 16], gen, __ATOMIC_RELEASE, __HIP_MEMORY_SCOPE_AGENT);
    }
    if (tid < 64) {
      // each lane polls 2 slots (128 blocks / 64 lanes), all in parallel
      while (__hip_atomic_load(&arrive[tid * 16], __ATOMIC_RELAXED,
                               __HIP_MEMORY_SCOPE_AGENT) < gen) {}
      while (__hip_atomic_load(&arrive[(tid + 64) * 16], __ATOMIC_RELAXED,
                               __HIP_MEMORY_SCOPE_AGENT) < gen) {}
      __threadfence();  // import other blocks' h stores (cache invalidate)
    }
    __syncthreads();
  }
}

// ws layout: [0, 8192) arrival slots (128 x 64B), [8192, +262144) h double
// buffer, then (optional, if ws_size permits) xe bf16 time-major (33.5 MB).
extern "C" void kernel_launch(void* const* d_in, const int* in_sizes, int n_in,
                              void* d_out, int out_size, void* d_ws, size_t ws_size,
                              hipStream_t stream) {
  const int*   X  = (const int*)d_in[0];
  const float* E  = (const float*)d_in[1];
  const float* Wi = (const float*)d_in[2];
  const float* bi = (const float*)d_in[3];
  const float* Wf = (const float*)d_in[4];
  const float* bf = (const float*)d_in[5];
  const float* Wo = (const float*)d_in[6];
  const float* bo = (const float*)d_in[7];
  const float* Wh = (const float*)d_in[8];
  const float* bh = (const float*)d_in[9];
  float* out = (float*)d_out;

  char* ws = (char*)d_ws;
  int* arrive = (int*)ws;
  unsigned short* hb = (unsigned short*)(ws + 8192);
  const size_t xe_off = 8192 + 2 * (size_t)NB * HIDN * sizeof(unsigned short);
  const size_t xe_bytes = (size_t)LSEQ * NB * EMB * sizeof(unsigned short);
  const bool use_xe = ws_size >= xe_off + xe_bytes;
  unsigned short* xe = use_xe ? (unsigned short*)(ws + xe_off) : nullptr;

  hipMemsetAsync(ws, 0, xe_off, stream);  // zero barrier slots + h_0

  if (use_xe)
    prep_x_kernel<<<dim3(LSEQ, NB), dim3(64), 0, stream>>>(X, E, xe);

  void* args[] = { (void*)&X, (void*)&E, (void*)&xe,
                   (void*)&Wi, (void*)&bi, (void*)&Wf, (void*)&bf,
                   (void*)&Wo, (void*)&bo, (void*)&Wh, (void*)&bh,
                   (void*)&out, (void*)&hb, (void*)&arrive };
  if (use_xe)
    hipLaunchCooperativeKernel(reinterpret_cast<void*>(lstm_main<true>),
                               dim3(GRID_MAIN), dim3(256), args, 0, stream);
  else
    hipLaunchCooperativeKernel(reinterpret_cast<void*>(lstm_main<false>),
                               dim3(GRID_MAIN), dim3(256), args, 0, stream);
}